// Round 7
// baseline (497.087 us; speedup 1.0000x reference)
//
#include <hip/hip_runtime.h>
#include <hip/hip_bf16.h>
#include <cstdint>
#include <cstddef>

constexpr int Cc = 2048;         // sequence length
constexpr int Mrows = 8192;      // B*C
constexpr float SC2 = 0.18033688011112042f;   // 0.125 * log2(e)

typedef __attribute__((ext_vector_type(8))) short short8;
typedef __attribute__((ext_vector_type(4))) float floatx4;
typedef unsigned short us;

#define MFMA_BF16(a, b, c) __builtin_amdgcn_mfma_f32_16x16x32_bf16((a), (b), (c), 0, 0, 0)
#define EXP2F(x) __builtin_amdgcn_exp2f(x)

__device__ __forceinline__ us f2bf(float f) {
  union { float f; unsigned u; } v; v.f = f;
  unsigned r = v.u + 0x7fffu + ((v.u >> 16) & 1u);   // RNE
  return (us)(r >> 16);
}
__device__ __forceinline__ float bf2f(us u) {
  union { unsigned u; float f; } v; v.u = ((unsigned)u) << 16;
  return v.f;
}
__device__ __forceinline__ uint2 pack4bf(float e0, float e1, float e2, float e3) {
  union { __hip_bfloat162 h; unsigned u; } a, b;
  a.h = __float22bfloat162_rn(float2{e0, e1});
  b.h = __float22bfloat162_rn(float2{e2, e3});
  return uint2{a.u, b.u};
}
// async global->LDS, 16B/lane; LDS dst = wave-uniform base + lane*16
__device__ __forceinline__ void async16(const us* g, us* l) {
  __builtin_amdgcn_global_load_lds(
      (const __attribute__((address_space(1))) unsigned int*)(g),
      (__attribute__((address_space(3))) unsigned int*)(l), 16, 0, 0);
}

// ---------------------------------------------------------------------------
// Cast x + 4 weights fp32 -> bf16 (wq|wk|wv land contiguously = fused W).
// ---------------------------------------------------------------------------
__global__ __launch_bounds__(256) void cast_all(
    const float* __restrict__ x,  const float* __restrict__ mq,
    const float* __restrict__ mk, const float* __restrict__ mv,
    const float* __restrict__ wo,
    us* __restrict__ xb, us* __restrict__ wqb, us* __restrict__ wkb,
    us* __restrict__ wvb, us* __restrict__ wob)
{
  size_t i = ((size_t)blockIdx.x * 256 + threadIdx.x) * 8;
  const float* src; us* dst; size_t j;
  if      (i <  8388608) { src = x;  dst = xb;  j = i; }
  else if (i <  8912896) { src = mq; dst = wqb; j = i -  8388608; }
  else if (i <  9437184) { src = mk; dst = wkb; j = i -  8912896; }
  else if (i < 10485760) { src = mv; dst = wvb; j = i -  9437184; }
  else if (i < 11534336) { src = wo; dst = wob; j = i - 10485760; }
  else return;
  float4 a = *(const float4*)(src + j);
  float4 b = *(const float4*)(src + j + 4);
  short8 o;
  o[0] = (short)f2bf(a.x); o[1] = (short)f2bf(a.y);
  o[2] = (short)f2bf(a.z); o[3] = (short)f2bf(a.w);
  o[4] = (short)f2bf(b.x); o[5] = (short)f2bf(b.y);
  o[6] = (short)f2bf(b.z); o[7] = (short)f2bf(b.w);
  *(short8*)(dst + j) = o;
}

// ---------------------------------------------------------------------------
// Fused QKV GEMM: [Q|K|V](8192x2048) = x(8192x1024) @ Wall(2048x1024)^T + b.
// 128x128 tile, BK=64, async staging + XOR swizzle. XCD-swizzled flat grid.
// ---------------------------------------------------------------------------
__global__ __launch_bounds__(256, 3) void gemm_qkv(
    const us* __restrict__ A, const us* __restrict__ Wall,
    const float* __restrict__ bq, const float* __restrict__ bk,
    const float* __restrict__ bv,
    us* __restrict__ Qo, us* __restrict__ Ko, us* __restrict__ Vo)
{
  __shared__ __align__(16) us As[128 * 64];
  __shared__ __align__(16) us Ws[128 * 64];
  const int t = threadIdx.x, lane = t & 63, wid = t >> 6;
  const int wr = wid >> 1, wc = wid & 1;
  const int quad = lane >> 4, l15 = lane & 15, l7 = l15 & 7;
  const int id = blockIdx.x;
  const int nt = (id & 7) * 2 + ((id >> 3) & 1);
  const int mt = id >> 4;
  const int m0 = mt * 128, n0 = nt * 128;
  const int K = 1024;

  floatx4 acc[4][4];
#pragma unroll
  for (int i = 0; i < 4; i++)
#pragma unroll
    for (int j = 0; j < 4; j++) acc[i][j] = (floatx4){0.f, 0.f, 0.f, 0.f};

  for (int k0 = 0; k0 < K; k0 += 64) {
    __syncthreads();
#pragma unroll
    for (int j = 0; j < 4; j++) {
      int f = (wid * 4 + j) * 64 + lane;
      int row = f >> 3, sc = (f & 7) ^ (row & 7);
      async16(A    + (size_t)(m0 + row) * K + k0 + sc * 8, &As[f * 8]);
      async16(Wall + (size_t)(n0 + row) * K + k0 + sc * 8, &Ws[f * 8]);
    }
    __syncthreads();
    short8 aF[4][2], bF[4][2];
#pragma unroll
    for (int fm = 0; fm < 4; fm++) {
      int ra = wr * 64 + fm * 16 + l15;
      int rb = wc * 64 + fm * 16 + l15;
#pragma unroll
      for (int c = 0; c < 2; c++) {
        aF[fm][c] = *(const short8*)&As[ra * 64 + (((c << 2) + quad) ^ l7) * 8];
        bF[fm][c] = *(const short8*)&Ws[rb * 64 + (((c << 2) + quad) ^ l7) * 8];
      }
    }
#pragma unroll
    for (int i = 0; i < 4; i++)
#pragma unroll
      for (int j = 0; j < 4; j++) {
        floatx4 d = MFMA_BF16(aF[i][0], bF[j][0], acc[i][j]);
        acc[i][j] = MFMA_BF16(aF[i][1], bF[j][1], d);
      }
  }

  us* dst; const float* bias; int Nout, c0;
  if (nt < 4)      { dst = Qo; bias = bq; Nout = 512;  c0 = n0; }
  else if (nt < 8) { dst = Ko; bias = bk; Nout = 512;  c0 = n0 - 512; }
  else             { dst = Vo; bias = bv; Nout = 1024; c0 = n0 - 1024; }

#pragma unroll
  for (int fn = 0; fn < 4; fn++) {
    int col = c0 + wc * 64 + fn * 16 + l15;
    float bvv = bias[col];
#pragma unroll
    for (int fm = 0; fm < 4; fm++)
#pragma unroll
      for (int r = 0; r < 4; r++) {
        int m = m0 + wr * 64 + fm * 16 + quad * 4 + r;
        dst[(size_t)m * Nout + col] = f2bf(acc[fm][fn][r] + bvv);
      }
  }
}

// ---------------------------------------------------------------------------
// Output GEMM: out(8192x1024 fp32) = Ab @ Wo^T + b. XCD-swizzled.
// ---------------------------------------------------------------------------
__global__ __launch_bounds__(256, 3) void gemm_out(
    const us* __restrict__ A, const us* __restrict__ W,
    const float* __restrict__ bias, float* __restrict__ outp)
{
  __shared__ __align__(16) us As[128 * 64];
  __shared__ __align__(16) us Ws[128 * 64];
  const int t = threadIdx.x, lane = t & 63, wid = t >> 6;
  const int wr = wid >> 1, wc = wid & 1;
  const int quad = lane >> 4, l15 = lane & 15, l7 = l15 & 7;
  const int id = blockIdx.x;
  const int m0 = (id >> 3) * 128, n0 = (id & 7) * 128;
  const int K = 1024, N = 1024;

  floatx4 acc[4][4];
#pragma unroll
  for (int i = 0; i < 4; i++)
#pragma unroll
    for (int j = 0; j < 4; j++) acc[i][j] = (floatx4){0.f, 0.f, 0.f, 0.f};

  for (int k0 = 0; k0 < K; k0 += 64) {
    __syncthreads();
#pragma unroll
    for (int j = 0; j < 4; j++) {
      int f = (wid * 4 + j) * 64 + lane;
      int row = f >> 3, sc = (f & 7) ^ (row & 7);
      async16(A + (size_t)(m0 + row) * K + k0 + sc * 8, &As[f * 8]);
      async16(W + (size_t)(n0 + row) * K + k0 + sc * 8, &Ws[f * 8]);
    }
    __syncthreads();
    short8 aF[4][2], bF[4][2];
#pragma unroll
    for (int fm = 0; fm < 4; fm++) {
      int ra = wr * 64 + fm * 16 + l15;
      int rb = wc * 64 + fm * 16 + l15;
#pragma unroll
      for (int c = 0; c < 2; c++) {
        aF[fm][c] = *(const short8*)&As[ra * 64 + (((c << 2) + quad) ^ l7) * 8];
        bF[fm][c] = *(const short8*)&Ws[rb * 64 + (((c << 2) + quad) ^ l7) * 8];
      }
    }
#pragma unroll
    for (int i = 0; i < 4; i++)
#pragma unroll
      for (int j = 0; j < 4; j++) {
        floatx4 d = MFMA_BF16(aF[i][0], bF[j][0], acc[i][j]);
        acc[i][j] = MFMA_BF16(aF[i][1], bF[j][1], d);
      }
  }

#pragma unroll
  for (int fn = 0; fn < 4; fn++) {
    int col = n0 + wc * 64 + fn * 16 + l15;
    float bvv = bias[col];
#pragma unroll
    for (int fm = 0; fm < 4; fm++)
#pragma unroll
      for (int r = 0; r < 4; r++) {
        int m = m0 + wr * 64 + fm * 16 + quad * 4 + r;
        outp[(size_t)m * N + col] = acc[fm][fn][r] + bvv;
      }
  }
}

// ---------------------------------------------------------------------------
// Pass 1: invZ[bh,k] = 1 / sum_q exp((q.k + mask[b,q])/8)  (softmax over q).
// k-tile 64 (16 keys/wave, K A-frags in regs), grid 1024 = one full round at
// 4 blocks/CU. Q double-buffered via DMA.
// ---------------------------------------------------------------------------
__global__ __launch_bounds__(256, 4) void attn_pass1(
    const us* __restrict__ Q_, const us* __restrict__ K_,
    const float* __restrict__ mask, float* __restrict__ invZ)
{
  __shared__ __align__(16) us Qs[2][128 * 64];
  const int t = threadIdx.x, lane = t & 63, wid = t >> 6;
  const int quad = lane >> 4, l15 = lane & 15, l7 = l15 & 7;
  const int id = blockIdx.x;
  const int bh = (id & 7) * 4 + ((id >> 3) & 3);
  const int kt = (id >> 5) * 64;
  const int b = bh >> 3;
  const us* Kb = K_ + (size_t)bh * Cc * 64;
  const us* Qb = Q_ + (size_t)bh * Cc * 64;
  const float* mrow = mask + (size_t)b * Cc;

  short8 kA[2];
#pragma unroll
  for (int c = 0; c < 2; c++)
    kA[c] = *(const short8*)(Kb + (size_t)(kt + wid * 16 + l15) * 64 + c * 32 + quad * 8);

  float zacc[4] = {};

#pragma unroll
  for (int j = 0; j < 4; j++) {   // stage tile 0
    int f = (wid * 4 + j) * 64 + lane;
    int row = f >> 3, sc = (f & 7) ^ (row & 7);
    async16(Qb + (size_t)row * 64 + sc * 8, &Qs[0][f * 8]);
  }
  __syncthreads();

  int p = 0;
  for (int it = 0; it < 16; it++) {
    if (it + 1 < 16) {
#pragma unroll
      for (int j = 0; j < 4; j++) {
        int f = (wid * 4 + j) * 64 + lane;
        int row = f >> 3, sc = (f & 7) ^ (row & 7);
        async16(Qb + (size_t)((it + 1) * 128 + row) * 64 + sc * 8, &Qs[1 - p][f * 8]);
      }
    }
    const us* Qsp = Qs[p];
#pragma unroll
    for (int qf = 0; qf < 8; qf++) {
      int row = qf * 16 + l15;
      short8 q0 = *(const short8*)&Qsp[row * 64 + ((quad) ^ l7) * 8];
      short8 q1 = *(const short8*)&Qsp[row * 64 + ((4 + quad) ^ l7) * 8];
      float mv = mrow[it * 128 + qf * 16 + l15] * SC2;
      floatx4 d = (floatx4){0.f, 0.f, 0.f, 0.f};
      d = MFMA_BF16(kA[0], q0, d);
      d = MFMA_BF16(kA[1], q1, d);
#pragma unroll
      for (int r = 0; r < 4; r++)
        zacc[r] += EXP2F(fmaf(d[r], SC2, mv));
    }
    __syncthreads();
    p ^= 1;
  }

#pragma unroll
  for (int r = 0; r < 4; r++) {
    float v = zacc[r];
    v += __shfl_xor(v, 1); v += __shfl_xor(v, 2);
    v += __shfl_xor(v, 4); v += __shfl_xor(v, 8);
    if (l15 == 0)
      invZ[(size_t)bh * Cc + kt + wid * 16 + quad * 4 + r] = 1.0f / v;
  }
}

// ---------------------------------------------------------------------------
// Transpose + scale: VT[bh][dv][c] = V[bh][c][dv] * invZ[bh][c]  (bf16).
// ---------------------------------------------------------------------------
__global__ __launch_bounds__(256) void transpose_v(
    const us* __restrict__ V, const float* __restrict__ invZ,
    us* __restrict__ VT)
{
  __shared__ __align__(16) us Vs[32][136];
  __shared__ float izs[32];
  const int bh = blockIdx.y, ct = blockIdx.x * 32;
  const int t = threadIdx.x;
  const us* Vb  = V  + (size_t)bh * Cc * 128;
  us*       VTb = VT + (size_t)bh * 128 * Cc;
#pragma unroll
  for (int i = 0; i < 2; i++) {
    int idx = t + i * 256, c = idx >> 4, d0 = (idx & 15) * 8;
    *(short8*)&Vs[c][d0] = *(const short8*)(Vb + (size_t)(ct + c) * 128 + d0);
  }
  if (t < 32) izs[t] = invZ[(size_t)bh * Cc + ct + t];
  __syncthreads();
#pragma unroll
  for (int i = 0; i < 2; i++) {
    int idx = t + i * 256, dv = idx >> 2, cb = (idx & 3) * 8;
    short8 o;
#pragma unroll
    for (int j = 0; j < 8; j++)
      o[j] = (short)f2bf(bf2f(Vs[cb + j][dv]) * izs[cb + j]);
    *(short8*)(VTb + (size_t)dv * Cc + ct + cb) = o;
  }
}

// ---------------------------------------------------------------------------
// Pass 2: A[q,:] = sum_k exp((q.k+mask[q])/8) * Vscaled[k,:].
// Flat grid 512, XCD swizzle. LDS = Ps[2] only (32 KB) -> 3 blocks/CU.
// VT B-frags live in REGISTERS, software-pipelined one K-iteration ahead
// (loads issue right after the barrier; the S^T MFMA+exp stage covers the
// L2 latency; PV consumes last iteration's registers). K-frags likewise
// one iteration ahead. One barrier per iteration.
// ---------------------------------------------------------------------------
__global__ __launch_bounds__(256, 3) void attn_pass2(
    const us* __restrict__ Q_, const us* __restrict__ K_,
    const us* __restrict__ VT_, const float* __restrict__ mask,
    us* __restrict__ Ab)
{
  __shared__ __align__(16) us Ps[2][128 * 64];    // 32 KB
  const int t = threadIdx.x, lane = t & 63, wid = t >> 6;
  const int quad = lane >> 4, l15 = lane & 15, l7 = l15 & 7;
  const int id = blockIdx.x;
  const int bh = (id & 7) * 4 + ((id >> 3) & 3);
  const int qt = (id >> 5) * 128;
  const int b = bh >> 3;
  const us* Qb  = Q_  + (size_t)bh * Cc * 64;
  const us* Kb  = K_  + (size_t)bh * Cc * 64;
  const us* VTb = VT_ + (size_t)bh * 128 * Cc;

  const int kHalf = wid & 1, qHalfS = wid >> 1;   // S^T split
  const int qPV = wid & 1, dvPV = wid >> 1;       // PV split

  // Q B-frags + prescaled mask for this wave's S^T q-range
  short8 qB[4][2];
  float mv2[4];
#pragma unroll
  for (int qq = 0; qq < 4; qq++) {
    int q = qt + qHalfS * 64 + qq * 16 + l15;
#pragma unroll
    for (int c = 0; c < 2; c++)
      qB[qq][c] = *(const short8*)(Qb + (size_t)q * 64 + c * 32 + quad * 8);
    mv2[qq] = mask[(size_t)b * Cc + q] * SC2;
  }

  floatx4 acc[4][4];
#pragma unroll
  for (int i = 0; i < 4; i++)
#pragma unroll
    for (int j = 0; j < 4; j++) acc[i][j] = (floatx4){0.f, 0.f, 0.f, 0.f};

  // K frags for kb=0
  short8 kA[2][2];
#pragma unroll
  for (int kk = 0; kk < 2; kk++)
#pragma unroll
    for (int c = 0; c < 2; c++)
      kA[kk][c] = *(const short8*)(Kb + (size_t)((kHalf * 2 + kk) * 16 + l15) * 64 + c * 32 + quad * 8);

  // VT frags for kb=0 (PV operands, registers)
  short8 vCur[4][2];
#pragma unroll
  for (int fn = 0; fn < 4; fn++) {
    const us* vrow = VTb + (size_t)(dvPV * 64 + fn * 16 + l15) * Cc;
#pragma unroll
    for (int kc = 0; kc < 2; kc++)
      vCur[fn][kc] = *(const short8*)(vrow + kc * 32 + quad * 8);
  }

  // prologue: S^T(0) -> Ps[0]
#pragma unroll
  for (int kk = 0; kk < 2; kk++) {
    int kf = kHalf * 2 + kk;
#pragma unroll
    for (int qq = 0; qq < 4; qq++) {
      floatx4 d = (floatx4){0.f, 0.f, 0.f, 0.f};
      d = MFMA_BF16(kA[kk][0], qB[qq][0], d);
      d = MFMA_BF16(kA[kk][1], qB[qq][1], d);
      uint2 pk = pack4bf(EXP2F(fmaf(d[0], SC2, mv2[qq])),
                         EXP2F(fmaf(d[1], SC2, mv2[qq])),
                         EXP2F(fmaf(d[2], SC2, mv2[qq])),
                         EXP2F(fmaf(d[3], SC2, mv2[qq])));
      int prow = qHalfS * 64 + qq * 16 + l15;
      *(uint2*)&Ps[0][prow * 64 + (((kf << 1) + (quad >> 1)) ^ l7) * 8 + (quad & 1) * 4] = pk;
    }
  }
  // preload K frags for kb=64
#pragma unroll
  for (int kk = 0; kk < 2; kk++)
#pragma unroll
    for (int c = 0; c < 2; c++)
      kA[kk][c] = *(const short8*)(Kb + (size_t)(64 + (kHalf * 2 + kk) * 16 + l15) * 64 + c * 32 + quad * 8);
  __syncthreads();

  int s = 0;
  for (int kb = 0; kb < Cc; kb += 64) {
    short8 vNext[4][2];
    if (kb + 64 < Cc) {
      // issue next VT loads FIRST (latency covered by S^T below)
#pragma unroll
      for (int fn = 0; fn < 4; fn++) {
        const us* vrow = VTb + (size_t)(dvPV * 64 + fn * 16 + l15) * Cc + kb + 64;
#pragma unroll
        for (int kc = 0; kc < 2; kc++)
          vNext[fn][kc] = *(const short8*)(vrow + kc * 32 + quad * 8);
      }
      // S^T(kb+64) -> Ps[1-s]  (kA holds keys of kb+64)
#pragma unroll
      for (int kk = 0; kk < 2; kk++) {
        int kf = kHalf * 2 + kk;
#pragma unroll
        for (int qq = 0; qq < 4; qq++) {
          floatx4 d = (floatx4){0.f, 0.f, 0.f, 0.f};
          d = MFMA_BF16(kA[kk][0], qB[qq][0], d);
          d = MFMA_BF16(kA[kk][1], qB[qq][1], d);
          uint2 pk = pack4bf(EXP2F(fmaf(d[0], SC2, mv2[qq])),
                             EXP2F(fmaf(d[1], SC2, mv2[qq])),
                             EXP2F(fmaf(d[2], SC2, mv2[qq])),
                             EXP2F(fmaf(d[3], SC2, mv2[qq])));
          int prow = qHalfS * 64 + qq * 16 + l15;
          *(uint2*)&Ps[1 - s][prow * 64 + (((kf << 1) + (quad >> 1)) ^ l7) * 8 + (quad & 1) * 4] = pk;
        }
      }
      if (kb + 128 < Cc) {   // reload K frags for kb+128
#pragma unroll
        for (int kk = 0; kk < 2; kk++)
#pragma unroll
          for (int c = 0; c < 2; c++)
            kA[kk][c] = *(const short8*)(Kb + (size_t)(kb + 128 + (kHalf * 2 + kk) * 16 + l15) * 64 + c * 32 + quad * 8);
      }
    }

    // PV(kb): wave's 64 q x 64 dv; P from LDS, V from registers (vCur)
    short8 pA[4][2];
#pragma unroll
    for (int qq = 0; qq < 4; qq++) {
      int prow = qPV * 64 + qq * 16 + l15;
#pragma unroll
      for (int kc = 0; kc < 2; kc++)
        pA[qq][kc] = *(const short8*)&Ps[s][prow * 64 + (((kc << 2) + quad) ^ l7) * 8];
    }
#pragma unroll
    for (int fn = 0; fn < 4; fn++)
#pragma unroll
      for (int kc = 0; kc < 2; kc++)
#pragma unroll
        for (int qq = 0; qq < 4; qq++)
          acc[qq][fn] = MFMA_BF16(pA[qq][kc], vCur[fn][kc], acc[qq][fn]);

    __syncthreads();
    s ^= 1;
    if (kb + 64 < Cc) {
#pragma unroll
      for (int fn = 0; fn < 4; fn++)
#pragma unroll
        for (int kc = 0; kc < 2; kc++)
          vCur[fn][kc] = vNext[fn][kc];
    }
  }

#pragma unroll
  for (int qq = 0; qq < 4; qq++)
#pragma unroll
    for (int fn = 0; fn < 4; fn++)
#pragma unroll
      for (int r = 0; r < 4; r++) {
        int q = qt + qPV * 64 + qq * 16 + quad * 4 + r;
        int dv = dvPV * 64 + fn * 16 + l15;
        Ab[((size_t)bh * Cc + q) * 128 + dv] = f2bf(acc[qq][fn][r]);
      }
}

// ---------------------------------------------------------------------------
extern "C" void kernel_launch(void* const* d_in, const int* in_sizes, int n_in,
                              void* d_out, int out_size, void* d_ws, size_t ws_size,
                              hipStream_t stream)
{
  const float* x    = (const float*)d_in[0];
  const float* mask = (const float*)d_in[1];
  const float* Mq_w = (const float*)d_in[2];
  const float* Mq_b = (const float*)d_in[3];
  const float* Mk_w = (const float*)d_in[4];
  const float* Mk_b = (const float*)d_in[5];
  const float* Mv_w = (const float*)d_in[6];
  const float* Mv_b = (const float*)d_in[7];
  const float* Wo_w = (const float*)d_in[8];
  const float* Wo_b = (const float*)d_in[9];
  float* outp = (float*)d_out;

  us* xb  = (us*)d_ws;
  us* wq  = xb  + 8388608;     // x:    8192x1024
  us* wk  = wq  + 524288;      // Mq_w: 512x1024   (wq|wk|wv contiguous = Wall)
  us* wv  = wk  + 524288;
  us* wo  = wv  + 1048576;     // Mv_w: 1024x1024
  us* Qb  = wo  + 1048576;     // Wo_w: 1024x1024
  us* Kb  = Qb  + 4194304;     // Q:    8192x512
  us* Vb  = Kb  + 4194304;
  us* VTb = Vb  + 8388608;     // V:    8192x1024
  us* Ab  = VTb + 8388608;     // VT:   32x128x2048
  float* invZ = (float*)(Ab + 8388608);   // 32x2048 fp32

  cast_all<<<5632, 256, 0, stream>>>(x, Mq_w, Mk_w, Mv_w, Wo_w, xb, wq, wk, wv, wo);

  gemm_qkv<<<1024, 256, 0, stream>>>(xb, wq, Mq_b, Mk_b, Mv_b, Qb, Kb, Vb);

  attn_pass1<<<1024, 256, 0, stream>>>(Qb, Kb, mask, invZ);
  transpose_v<<<dim3(64, 32), 256, 0, stream>>>(Vb, invZ, VTb);
  attn_pass2<<<512, 256, 0, stream>>>(Qb, Kb, VTb, mask, Ab);

  gemm_out<<<512, 256, 0, stream>>>(Ab, wo, Wo_b, outp);
}

// Round 8
// 295.414 us; speedup vs baseline: 1.6827x; 1.6827x over previous
//
#include <hip/hip_runtime.h>
#include <hip/hip_bf16.h>
#include <cstdint>
#include <cstddef>

constexpr int Cc = 2048;         // sequence length
constexpr int Mrows = 8192;      // B*C
constexpr float SC2 = 0.18033688011112042f;   // 0.125 * log2(e)

typedef __attribute__((ext_vector_type(8))) short short8;
typedef __attribute__((ext_vector_type(4))) float floatx4;
typedef unsigned short us;

#define MFMA_BF16(a, b, c) __builtin_amdgcn_mfma_f32_16x16x32_bf16((a), (b), (c), 0, 0, 0)
#define EXP2F(x) __builtin_amdgcn_exp2f(x)

__device__ __forceinline__ us f2bf(float f) {
  union { float f; unsigned u; } v; v.f = f;
  unsigned r = v.u + 0x7fffu + ((v.u >> 16) & 1u);   // RNE
  return (us)(r >> 16);
}
__device__ __forceinline__ float bf2f(us u) {
  union { unsigned u; float f; } v; v.u = ((unsigned)u) << 16;
  return v.f;
}
__device__ __forceinline__ uint2 pack4bf(float e0, float e1, float e2, float e3) {
  union { __hip_bfloat162 h; unsigned u; } a, b;
  a.h = __float22bfloat162_rn(float2{e0, e1});
  b.h = __float22bfloat162_rn(float2{e2, e3});
  return uint2{a.u, b.u};
}
// async global->LDS, 16B/lane; LDS dst = wave-uniform base + lane*16
__device__ __forceinline__ void async16(const us* g, us* l) {
  __builtin_amdgcn_global_load_lds(
      (const __attribute__((address_space(1))) unsigned int*)(g),
      (__attribute__((address_space(3))) unsigned int*)(l), 16, 0, 0);
}

// ---------------------------------------------------------------------------
// Cast x + 4 weights fp32 -> bf16 (wq|wk|wv land contiguously = fused W).
// ---------------------------------------------------------------------------
__global__ __launch_bounds__(256) void cast_all(
    const float* __restrict__ x,  const float* __restrict__ mq,
    const float* __restrict__ mk, const float* __restrict__ mv,
    const float* __restrict__ wo,
    us* __restrict__ xb, us* __restrict__ wqb, us* __restrict__ wkb,
    us* __restrict__ wvb, us* __restrict__ wob)
{
  size_t i = ((size_t)blockIdx.x * 256 + threadIdx.x) * 8;
  const float* src; us* dst; size_t j;
  if      (i <  8388608) { src = x;  dst = xb;  j = i; }
  else if (i <  8912896) { src = mq; dst = wqb; j = i -  8388608; }
  else if (i <  9437184) { src = mk; dst = wkb; j = i -  8912896; }
  else if (i < 10485760) { src = mv; dst = wvb; j = i -  9437184; }
  else if (i < 11534336) { src = wo; dst = wob; j = i - 10485760; }
  else return;
  float4 a = *(const float4*)(src + j);
  float4 b = *(const float4*)(src + j + 4);
  short8 o;
  o[0] = (short)f2bf(a.x); o[1] = (short)f2bf(a.y);
  o[2] = (short)f2bf(a.z); o[3] = (short)f2bf(a.w);
  o[4] = (short)f2bf(b.x); o[5] = (short)f2bf(b.y);
  o[6] = (short)f2bf(b.z); o[7] = (short)f2bf(b.w);
  *(short8*)(dst + j) = o;
}

// ---------------------------------------------------------------------------
// Fused QKV GEMM: [Q|K|V](8192x2048) = x(8192x1024) @ Wall(2048x1024)^T + b.
// ---------------------------------------------------------------------------
__global__ __launch_bounds__(256, 3) void gemm_qkv(
    const us* __restrict__ A, const us* __restrict__ Wall,
    const float* __restrict__ bq, const float* __restrict__ bk,
    const float* __restrict__ bv,
    us* __restrict__ Qo, us* __restrict__ Ko, us* __restrict__ Vo)
{
  __shared__ __align__(16) us As[128 * 64];
  __shared__ __align__(16) us Ws[128 * 64];
  const int t = threadIdx.x, lane = t & 63, wid = t >> 6;
  const int wr = wid >> 1, wc = wid & 1;
  const int quad = lane >> 4, l15 = lane & 15, l7 = l15 & 7;
  const int id = blockIdx.x;
  const int nt = (id & 7) * 2 + ((id >> 3) & 1);
  const int mt = id >> 4;
  const int m0 = mt * 128, n0 = nt * 128;
  const int K = 1024;

  floatx4 acc[4][4];
#pragma unroll
  for (int i = 0; i < 4; i++)
#pragma unroll
    for (int j = 0; j < 4; j++) acc[i][j] = (floatx4){0.f, 0.f, 0.f, 0.f};

  for (int k0 = 0; k0 < K; k0 += 64) {
    __syncthreads();
#pragma unroll
    for (int j = 0; j < 4; j++) {
      int f = (wid * 4 + j) * 64 + lane;
      int row = f >> 3, sc = (f & 7) ^ (row & 7);
      async16(A    + (size_t)(m0 + row) * K + k0 + sc * 8, &As[f * 8]);
      async16(Wall + (size_t)(n0 + row) * K + k0 + sc * 8, &Ws[f * 8]);
    }
    __syncthreads();
    short8 aF[4][2], bF[4][2];
#pragma unroll
    for (int fm = 0; fm < 4; fm++) {
      int ra = wr * 64 + fm * 16 + l15;
      int rb = wc * 64 + fm * 16 + l15;
#pragma unroll
      for (int c = 0; c < 2; c++) {
        aF[fm][c] = *(const short8*)&As[ra * 64 + (((c << 2) + quad) ^ l7) * 8];
        bF[fm][c] = *(const short8*)&Ws[rb * 64 + (((c << 2) + quad) ^ l7) * 8];
      }
    }
#pragma unroll
    for (int i = 0; i < 4; i++)
#pragma unroll
      for (int j = 0; j < 4; j++) {
        floatx4 d = MFMA_BF16(aF[i][0], bF[j][0], acc[i][j]);
        acc[i][j] = MFMA_BF16(aF[i][1], bF[j][1], d);
      }
  }

  us* dst; const float* bias; int Nout, c0;
  if (nt < 4)      { dst = Qo; bias = bq; Nout = 512;  c0 = n0; }
  else if (nt < 8) { dst = Ko; bias = bk; Nout = 512;  c0 = n0 - 512; }
  else             { dst = Vo; bias = bv; Nout = 1024; c0 = n0 - 1024; }

#pragma unroll
  for (int fn = 0; fn < 4; fn++) {
    int col = c0 + wc * 64 + fn * 16 + l15;
    float bvv = bias[col];
#pragma unroll
    for (int fm = 0; fm < 4; fm++)
#pragma unroll
      for (int r = 0; r < 4; r++) {
        int m = m0 + wr * 64 + fm * 16 + quad * 4 + r;
        dst[(size_t)m * Nout + col] = f2bf(acc[fm][fn][r] + bvv);
      }
  }
}

// ---------------------------------------------------------------------------
// Output GEMM: out(8192x1024 fp32) = Ab @ Wo^T + b. XCD-swizzled.
// ---------------------------------------------------------------------------
__global__ __launch_bounds__(256, 3) void gemm_out(
    const us* __restrict__ A, const us* __restrict__ W,
    const float* __restrict__ bias, float* __restrict__ outp)
{
  __shared__ __align__(16) us As[128 * 64];
  __shared__ __align__(16) us Ws[128 * 64];
  const int t = threadIdx.x, lane = t & 63, wid = t >> 6;
  const int wr = wid >> 1, wc = wid & 1;
  const int quad = lane >> 4, l15 = lane & 15, l7 = l15 & 7;
  const int id = blockIdx.x;
  const int m0 = (id >> 3) * 128, n0 = (id & 7) * 128;
  const int K = 1024, N = 1024;

  floatx4 acc[4][4];
#pragma unroll
  for (int i = 0; i < 4; i++)
#pragma unroll
    for (int j = 0; j < 4; j++) acc[i][j] = (floatx4){0.f, 0.f, 0.f, 0.f};

  for (int k0 = 0; k0 < K; k0 += 64) {
    __syncthreads();
#pragma unroll
    for (int j = 0; j < 4; j++) {
      int f = (wid * 4 + j) * 64 + lane;
      int row = f >> 3, sc = (f & 7) ^ (row & 7);
      async16(A + (size_t)(m0 + row) * K + k0 + sc * 8, &As[f * 8]);
      async16(W + (size_t)(n0 + row) * K + k0 + sc * 8, &Ws[f * 8]);
    }
    __syncthreads();
    short8 aF[4][2], bF[4][2];
#pragma unroll
    for (int fm = 0; fm < 4; fm++) {
      int ra = wr * 64 + fm * 16 + l15;
      int rb = wc * 64 + fm * 16 + l15;
#pragma unroll
      for (int c = 0; c < 2; c++) {
        aF[fm][c] = *(const short8*)&As[ra * 64 + (((c << 2) + quad) ^ l7) * 8];
        bF[fm][c] = *(const short8*)&Ws[rb * 64 + (((c << 2) + quad) ^ l7) * 8];
      }
    }
#pragma unroll
    for (int i = 0; i < 4; i++)
#pragma unroll
      for (int j = 0; j < 4; j++) {
        floatx4 d = MFMA_BF16(aF[i][0], bF[j][0], acc[i][j]);
        acc[i][j] = MFMA_BF16(aF[i][1], bF[j][1], d);
      }
  }

#pragma unroll
  for (int fn = 0; fn < 4; fn++) {
    int col = n0 + wc * 64 + fn * 16 + l15;
    float bvv = bias[col];
#pragma unroll
    for (int fm = 0; fm < 4; fm++)
#pragma unroll
      for (int r = 0; r < 4; r++) {
        int m = m0 + wr * 64 + fm * 16 + quad * 4 + r;
        outp[(size_t)m * N + col] = acc[fm][fn][r] + bvv;
      }
  }
}

// ---------------------------------------------------------------------------
// Pass 1: invZ[bh,k] = 1 / sum_q exp((q.k + mask[b,q])/8)  (softmax over q).
// ---------------------------------------------------------------------------
__global__ __launch_bounds__(256, 4) void attn_pass1(
    const us* __restrict__ Q_, const us* __restrict__ K_,
    const float* __restrict__ mask, float* __restrict__ invZ)
{
  __shared__ __align__(16) us Qs[2][128 * 64];
  const int t = threadIdx.x, lane = t & 63, wid = t >> 6;
  const int quad = lane >> 4, l15 = lane & 15, l7 = l15 & 7;
  const int id = blockIdx.x;
  const int bh = (id & 7) * 4 + ((id >> 3) & 3);
  const int kt = (id >> 5) * 64;
  const int b = bh >> 3;
  const us* Kb = K_ + (size_t)bh * Cc * 64;
  const us* Qb = Q_ + (size_t)bh * Cc * 64;
  const float* mrow = mask + (size_t)b * Cc;

  short8 kA[2];
#pragma unroll
  for (int c = 0; c < 2; c++)
    kA[c] = *(const short8*)(Kb + (size_t)(kt + wid * 16 + l15) * 64 + c * 32 + quad * 8);

  float zacc[4] = {};

#pragma unroll
  for (int j = 0; j < 4; j++) {   // stage tile 0
    int f = (wid * 4 + j) * 64 + lane;
    int row = f >> 3, sc = (f & 7) ^ (row & 7);
    async16(Qb + (size_t)row * 64 + sc * 8, &Qs[0][f * 8]);
  }
  __syncthreads();

  int p = 0;
  for (int it = 0; it < 16; it++) {
    if (it + 1 < 16) {
#pragma unroll
      for (int j = 0; j < 4; j++) {
        int f = (wid * 4 + j) * 64 + lane;
        int row = f >> 3, sc = (f & 7) ^ (row & 7);
        async16(Qb + (size_t)((it + 1) * 128 + row) * 64 + sc * 8, &Qs[1 - p][f * 8]);
      }
    }
    const us* Qsp = Qs[p];
#pragma unroll
    for (int qf = 0; qf < 8; qf++) {
      int row = qf * 16 + l15;
      short8 q0 = *(const short8*)&Qsp[row * 64 + ((quad) ^ l7) * 8];
      short8 q1 = *(const short8*)&Qsp[row * 64 + ((4 + quad) ^ l7) * 8];
      float mv = mrow[it * 128 + qf * 16 + l15] * SC2;
      floatx4 d = (floatx4){0.f, 0.f, 0.f, 0.f};
      d = MFMA_BF16(kA[0], q0, d);
      d = MFMA_BF16(kA[1], q1, d);
#pragma unroll
      for (int r = 0; r < 4; r++)
        zacc[r] += EXP2F(fmaf(d[r], SC2, mv));
    }
    __syncthreads();
    p ^= 1;
  }

#pragma unroll
  for (int r = 0; r < 4; r++) {
    float v = zacc[r];
    v += __shfl_xor(v, 1); v += __shfl_xor(v, 2);
    v += __shfl_xor(v, 4); v += __shfl_xor(v, 8);
    if (l15 == 0)
      invZ[(size_t)bh * Cc + kt + wid * 16 + quad * 4 + r] = 1.0f / v;
  }
}

// ---------------------------------------------------------------------------
// Transpose + scale: VT[bh][dv][c] = V[bh][c][dv] * invZ[bh][c]  (bf16).
// ---------------------------------------------------------------------------
__global__ __launch_bounds__(256) void transpose_v(
    const us* __restrict__ V, const float* __restrict__ invZ,
    us* __restrict__ VT)
{
  __shared__ __align__(16) us Vs[32][136];
  __shared__ float izs[32];
  const int bh = blockIdx.y, ct = blockIdx.x * 32;
  const int t = threadIdx.x;
  const us* Vb  = V  + (size_t)bh * Cc * 128;
  us*       VTb = VT + (size_t)bh * 128 * Cc;
#pragma unroll
  for (int i = 0; i < 2; i++) {
    int idx = t + i * 256, c = idx >> 4, d0 = (idx & 15) * 8;
    *(short8*)&Vs[c][d0] = *(const short8*)(Vb + (size_t)(ct + c) * 128 + d0);
  }
  if (t < 32) izs[t] = invZ[(size_t)bh * Cc + ct + t];
  __syncthreads();
#pragma unroll
  for (int i = 0; i < 2; i++) {
    int idx = t + i * 256, dv = idx >> 2, cb = (idx & 3) * 8;
    short8 o;
#pragma unroll
    for (int j = 0; j < 8; j++)
      o[j] = (short)f2bf(bf2f(Vs[cb + j][dv]) * izs[cb + j]);
    *(short8*)(VTb + (size_t)dv * Cc + ct + cb) = o;
  }
}

// ---------------------------------------------------------------------------
// Pass-2 helpers (force-inlined; array params stay in registers after SROA).
// ---------------------------------------------------------------------------
__device__ __forceinline__ void p2_load_k(
    const us* Kb, int kb, short8 kA[2][2], int kHalf, int quad, int l15)
{
#pragma unroll
  for (int kk = 0; kk < 2; kk++)
#pragma unroll
    for (int c = 0; c < 2; c++)
      kA[kk][c] = *(const short8*)(Kb + (size_t)(kb + (kHalf * 2 + kk) * 16 + l15) * 64 + c * 32 + quad * 8);
}
__device__ __forceinline__ void p2_load_v(
    const us* VTb, int kb, short8 v[4][2], int dvPV, int quad, int l15)
{
#pragma unroll
  for (int fn = 0; fn < 4; fn++) {
    const us* vrow = VTb + (size_t)(dvPV * 64 + fn * 16 + l15) * Cc + kb;
#pragma unroll
    for (int kc = 0; kc < 2; kc++)
      v[fn][kc] = *(const short8*)(vrow + kc * 32 + quad * 8);
  }
}
__device__ __forceinline__ void p2_st(
    const short8 kA[2][2], const short8 qB[4][2], const float mv2[4],
    us* PsBuf, int kHalf, int qHalfS, int quad, int l15, int l7)
{
#pragma unroll
  for (int kk = 0; kk < 2; kk++) {
    int kf = kHalf * 2 + kk;
#pragma unroll
    for (int qq = 0; qq < 4; qq++) {
      floatx4 d = (floatx4){0.f, 0.f, 0.f, 0.f};
      d = MFMA_BF16(kA[kk][0], qB[qq][0], d);
      d = MFMA_BF16(kA[kk][1], qB[qq][1], d);
      uint2 pk = pack4bf(EXP2F(fmaf(d[0], SC2, mv2[qq])),
                         EXP2F(fmaf(d[1], SC2, mv2[qq])),
                         EXP2F(fmaf(d[2], SC2, mv2[qq])),
                         EXP2F(fmaf(d[3], SC2, mv2[qq])));
      int prow = qHalfS * 64 + qq * 16 + l15;
      *(uint2*)&PsBuf[prow * 64 + (((kf << 1) + (quad >> 1)) ^ l7) * 8 + (quad & 1) * 4] = pk;
    }
  }
}
__device__ __forceinline__ void p2_pv(
    const short8 v[4][2], const us* PsBuf, floatx4 acc[4][4],
    int qPV, int quad, int l15, int l7)
{
  short8 pA[4][2];
#pragma unroll
  for (int qq = 0; qq < 4; qq++) {
    int prow = qPV * 64 + qq * 16 + l15;
#pragma unroll
    for (int kc = 0; kc < 2; kc++)
      pA[qq][kc] = *(const short8*)&PsBuf[prow * 64 + (((kc << 2) + quad) ^ l7) * 8];
  }
#pragma unroll
  for (int fn = 0; fn < 4; fn++)
#pragma unroll
    for (int kc = 0; kc < 2; kc++)
#pragma unroll
      for (int qq = 0; qq < 4; qq++)
        acc[qq][fn] = MFMA_BF16(pA[qq][kc], v[fn][kc], acc[qq][fn]);
}

// ---------------------------------------------------------------------------
// Pass 2: A[q,:] = sum_k exp((q.k+mask[q])/8) * Vscaled[k,:].
// Flat grid 512, XCD swizzle. LDS = Ps[2] only (32 KB). V and K fragments in
// REGISTERS, software-pipelined via manual unroll-by-2 with two static
// register sets (vA/vB) -- no conditional register defs, no cross-barrier
// copies (the R7 spill triggers). launch_bounds(256,2): 256-VGPR budget.
// Prefetch loads are unconditional; tail OOB reads land in adjacent
// workspace buffers and are never consumed.
// ---------------------------------------------------------------------------
__global__ __launch_bounds__(256, 2) void attn_pass2(
    const us* __restrict__ Q_, const us* __restrict__ K_,
    const us* __restrict__ VT_, const float* __restrict__ mask,
    us* __restrict__ Ab)
{
  __shared__ __align__(16) us Ps[2][128 * 64];    // 32 KB
  const int t = threadIdx.x, lane = t & 63, wid = t >> 6;
  const int quad = lane >> 4, l15 = lane & 15, l7 = l15 & 7;
  const int id = blockIdx.x;
  const int bh = (id & 7) * 4 + ((id >> 3) & 3);
  const int qt = (id >> 5) * 128;
  const int b = bh >> 3;
  const us* Qb  = Q_  + (size_t)bh * Cc * 64;
  const us* Kb  = K_  + (size_t)bh * Cc * 64;
  const us* VTb = VT_ + (size_t)bh * 128 * Cc;

  const int kHalf = wid & 1, qHalfS = wid >> 1;   // S^T split
  const int qPV = wid & 1, dvPV = wid >> 1;       // PV split

  // Q B-frags + prescaled mask (resident all loop)
  short8 qB[4][2];
  float mv2[4];
#pragma unroll
  for (int qq = 0; qq < 4; qq++) {
    int q = qt + qHalfS * 64 + qq * 16 + l15;
#pragma unroll
    for (int c = 0; c < 2; c++)
      qB[qq][c] = *(const short8*)(Qb + (size_t)q * 64 + c * 32 + quad * 8);
    mv2[qq] = mask[(size_t)b * Cc + q] * SC2;
  }

  floatx4 acc[4][4];
#pragma unroll
  for (int i = 0; i < 4; i++)
#pragma unroll
    for (int j = 0; j < 4; j++) acc[i][j] = (floatx4){0.f, 0.f, 0.f, 0.f};

  short8 kA[2][2], vA[4][2], vB[4][2];

  // prologue: K(0), V(0), S^T(0)->Ps[0], K(64)
  p2_load_k(Kb, 0, kA, kHalf, quad, l15);
  p2_load_v(VTb, 0, vA, dvPV, quad, l15);
  p2_st(kA, qB, mv2, Ps[0], kHalf, qHalfS, quad, l15, l7);
  p2_load_k(Kb, 64, kA, kHalf, quad, l15);
  __syncthreads();

  for (int kb = 0; kb < Cc; kb += 128) {
    // even half: produce Ps[1]=S^T(kb+64); consume Ps[0]+vA for PV(kb)
    p2_load_v(VTb, kb + 64, vB, dvPV, quad, l15);           // always in-range
    p2_st(kA, qB, mv2, Ps[1], kHalf, qHalfS, quad, l15, l7);
    p2_load_k(Kb, kb + 128, kA, kHalf, quad, l15);          // benign OOB tail
    p2_pv(vA, Ps[0], acc, qPV, quad, l15, l7);
    __syncthreads();
    // odd half: produce Ps[0]=S^T(kb+128); consume Ps[1]+vB for PV(kb+64)
    p2_load_v(VTb, kb + 128, vA, dvPV, quad, l15);          // benign OOB tail
    if (kb + 128 < Cc)
      p2_st(kA, qB, mv2, Ps[0], kHalf, qHalfS, quad, l15, l7);
    p2_load_k(Kb, kb + 192, kA, kHalf, quad, l15);          // benign OOB tail
    p2_pv(vB, Ps[1], acc, qPV, quad, l15, l7);
    __syncthreads();
  }

#pragma unroll
  for (int qq = 0; qq < 4; qq++)
#pragma unroll
    for (int fn = 0; fn < 4; fn++)
#pragma unroll
      for (int r = 0; r < 4; r++) {
        int q = qt + qPV * 64 + qq * 16 + quad * 4 + r;
        int dv = dvPV * 64 + fn * 16 + l15;
        Ab[((size_t)bh * Cc + q) * 128 + dv] = f2bf(acc[qq][fn][r]);
      }
}

// ---------------------------------------------------------------------------
extern "C" void kernel_launch(void* const* d_in, const int* in_sizes, int n_in,
                              void* d_out, int out_size, void* d_ws, size_t ws_size,
                              hipStream_t stream)
{
  const float* x    = (const float*)d_in[0];
  const float* mask = (const float*)d_in[1];
  const float* Mq_w = (const float*)d_in[2];
  const float* Mq_b = (const float*)d_in[3];
  const float* Mk_w = (const float*)d_in[4];
  const float* Mk_b = (const float*)d_in[5];
  const float* Mv_w = (const float*)d_in[6];
  const float* Mv_b = (const float*)d_in[7];
  const float* Wo_w = (const float*)d_in[8];
  const float* Wo_b = (const float*)d_in[9];
  float* outp = (float*)d_out;

  us* xb  = (us*)d_ws;
  us* wq  = xb  + 8388608;     // x:    8192x1024
  us* wk  = wq  + 524288;      // Mq_w: 512x1024   (wq|wk|wv contiguous = Wall)
  us* wv  = wk  + 524288;
  us* wo  = wv  + 1048576;     // Mv_w: 1024x1024
  us* Qb  = wo  + 1048576;     // Wo_w: 1024x1024
  us* Kb  = Qb  + 4194304;     // Q:    8192x512
  us* Vb  = Kb  + 4194304;
  us* VTb = Vb  + 8388608;     // V:    8192x1024
  us* Ab  = VTb + 8388608;     // VT:   32x128x2048
  float* invZ = (float*)(Ab + 8388608);   // 32x2048 fp32

  cast_all<<<5632, 256, 0, stream>>>(x, Mq_w, Mk_w, Mv_w, Wo_w, xb, wq, wk, wv, wo);

  gemm_qkv<<<1024, 256, 0, stream>>>(xb, wq, Mq_b, Mk_b, Mv_b, Qb, Kb, Vb);

  attn_pass1<<<1024, 256, 0, stream>>>(Qb, Kb, mask, invZ);
  transpose_v<<<dim3(64, 32), 256, 0, stream>>>(Vb, invZ, VTb);
  attn_pass2<<<512, 256, 0, stream>>>(Qb, Kb, VTb, mask, Ab);

  gemm_out<<<512, 256, 0, stream>>>(Ab, wo, Wo_b, outp);
}